// Round 11
// baseline (205.932 us; speedup 1.0000x reference)
//
#include <hip/hip_runtime.h>
#include <hip/hip_bf16.h>

// Problem constants
#define T_DIM 8192
#define IN_DIM 1024
#define RES_DIM 4096

typedef unsigned short u16;
typedef _Float16 f16;
typedef f16 f16x8 __attribute__((ext_vector_type(8)));
typedef float f32x4 __attribute__((ext_vector_type(4)));
typedef float f32x16 __attribute__((ext_vector_type(16)));

// ---------- helpers ----------
__device__ __forceinline__ float tanh_fast(float z) {
    z = fminf(15.0f, fmaxf(-15.0f, z));          // avoid exp overflow
    float e = __expf(2.0f * z);
    float inv = __builtin_amdgcn_rcpf(e + 1.0f);
    return fmaf(-2.0f, inv, 1.0f);
}

__device__ __forceinline__ void stage16(const u16* g, u16* l) {
    __builtin_amdgcn_global_load_lds(
        (const __attribute__((address_space(1))) void*)g,
        (__attribute__((address_space(3))) void*)l, 16, 0, 0);
}

// ---------- fused convert: X -> (Xh, Xl) fp16 pair, W -> Wf fp16, tiled layout ----------
// Verified tile mapping: tile (rt, kt) rows rt*128..+128, k kt*32..+32;
// in-tile elem = kq*1024 + row*8 + e; chunk c = ((rt*32+kt)*4+kq)*128 + row.
__global__ void convert_all(const float* __restrict__ x, const float* __restrict__ Wsrc,
                            u16* __restrict__ Xh, u16* __restrict__ Xl,
                            u16* __restrict__ Wf, int nX, int nTot) {
    for (int g = blockIdx.x * blockDim.x + threadIdx.x; g < nTot;
         g += gridDim.x * blockDim.x) {
        const int isX = (g < nX);
        const int c   = isX ? g : (g - nX);
        int row = c & 127;
        int kq  = (c >> 7) & 3;
        int kt  = (c >> 9) & 31;
        int rt  = c >> 14;
        const float* src = (isX ? x : Wsrc) + (size_t)(rt * 128 + row) * 1024 + kt * 32 + kq * 8;
        float4 f0 = *(const float4*)src;
        float4 f1 = *(const float4*)(src + 4);
        float f[8] = {f0.x, f0.y, f0.z, f0.w, f1.x, f1.y, f1.z, f1.w};
        alignas(16) u16 hv[8];
        alignas(16) u16 lv[8];
#pragma unroll
        for (int e = 0; e < 8; ++e) {
            f16 h = (f16)f[e];
            f16 l = (f16)(f[e] - (float)h);
            hv[e] = *(const u16*)&h;
            lv[e] = *(const u16*)&l;
        }
        if (isX) {
            *(uint4*)(Xh + (size_t)c * 8) = *(const uint4*)hv;
            *(uint4*)(Xl + (size_t)c * 8) = *(const uint4*)lv;
        } else {
            *(uint4*)(Wf + (size_t)c * 8) = *(const uint4*)hv;
        }
    }
}

// ---------- GEMM: 2-pass fp16 MFMA, 128x256 tile, 64x128 wave blocks, BK=64 ----------
// Round-10 geometry (best measured: 136.5 us) with the barrier count halved:
// two 32-k sub-tiles staged per barrier pair (16 drain events instead of 32).
// LDS 64 KiB; occupancy unchanged (reg-capped at 2 waves/SIMD either way).
// launch_bounds(256,2) pins unified regs <= 256 so sub-tile fragments can't
// drop us to 1 wave/SIMD.
__global__ __launch_bounds__(256, 2)
void gemm_f16_wide2(const u16* __restrict__ Xh, const u16* __restrict__ Xl,
                    const u16* __restrict__ Wf, float* __restrict__ C) {
    __shared__ __attribute__((aligned(16))) u16 sAh[2][4096];
    __shared__ __attribute__((aligned(16))) u16 sAl[2][4096];
    __shared__ __attribute__((aligned(16))) u16 sW[2][2][4096];

    const int tid  = threadIdx.x;
    const int lane = tid & 63;
    const int wave = tid >> 6;
    const int wr = wave >> 1, wc = wave & 1;
    const int bm = blockIdx.x, bn = blockIdx.y;

    f32x16 acc[2][4] = {};   // [mf][nf], each 32x32

    const int l31 = lane & 31;
    const int kgl = lane >> 5;

    for (int ktp = 0; ktp < 16; ++ktp) {
        __syncthreads();   // WAR: previous iteration's LDS reads done
#pragma unroll
        for (int s = 0; s < 2; ++s) {
            const int kt = ktp * 2 + s;
            const u16* gX0 = Xh + ((size_t)(bm * 32 + kt)) * 4096;
            const u16* gX1 = Xl + ((size_t)(bm * 32 + kt)) * 4096;
            const u16* gW0 = Wf + ((size_t)((bn * 2 + 0) * 32 + kt)) * 4096;
            const u16* gW1 = Wf + ((size_t)((bn * 2 + 1) * 32 + kt)) * 4096;
#pragma unroll
            for (int i = 0; i < 2; ++i) {
                int off = i * 2048 + tid * 8;          // per-lane global elem offset
                int wb  = i * 2048 + (tid & ~63) * 8;  // wave-uniform LDS elem base
                stage16(gX0 + off, &sAh[s][0] + wb);
                stage16(gX1 + off, &sAl[s][0] + wb);
                stage16(gW0 + off, &sW[s][0][0] + wb);
                stage16(gW1 + off, &sW[s][1][0] + wb);
            }
        }
        __syncthreads();   // staging visible (compiler drains vmcnt at barrier)

#pragma unroll
        for (int s = 0; s < 2; ++s) {
            f16x8 ah[2][2], al8[2][2], bw[4][2];   // [mf|nf][ks]
#pragma unroll
            for (int mf = 0; mf < 2; ++mf)
#pragma unroll
                for (int ks = 0; ks < 2; ++ks) {
                    int ao = (ks * 2 + kgl) * 1024 + (wr * 64 + mf * 32 + l31) * 8;
                    ah[mf][ks]  = *(const f16x8*)(&sAh[s][0] + ao);
                    al8[mf][ks] = *(const f16x8*)(&sAl[s][0] + ao);
                }
#pragma unroll
            for (int nf = 0; nf < 4; ++nf)
#pragma unroll
                for (int ks = 0; ks < 2; ++ks) {
                    int bo = (ks * 2 + kgl) * 1024 + (nf * 32 + l31) * 8;
                    bw[nf][ks] = *(const f16x8*)(&sW[s][wc][0] + bo);
                }
#pragma unroll
            for (int mf = 0; mf < 2; ++mf)
#pragma unroll
                for (int nf = 0; nf < 4; ++nf)
#pragma unroll
                    for (int ks = 0; ks < 2; ++ks) {
                        acc[mf][nf] = __builtin_amdgcn_mfma_f32_32x32x16_f16(
                            ah[mf][ks], bw[nf][ks], acc[mf][nf], 0, 0, 0);
                        acc[mf][nf] = __builtin_amdgcn_mfma_f32_32x32x16_f16(
                            al8[mf][ks], bw[nf][ks], acc[mf][nf], 0, 0, 0);
                    }
        }
    }

    // epilogue: 32x32 C/D layout col = lane&31, row = (reg&3) + 8*(reg>>2) + 4*(lane>>5)
    // [m74/m101 verified, rounds 5-10 proven]
    const size_t t0 = (size_t)bm * 128 + wr * 64;
    const size_t c0 = (size_t)bn * 256 + wc * 128;
#pragma unroll
    for (int mf = 0; mf < 2; ++mf)
#pragma unroll
        for (int nf = 0; nf < 4; ++nf) {
            float* cp = C + (t0 + mf * 32) * RES_DIM + (c0 + nf * 32 + l31);
#pragma unroll
            for (int r = 0; r < 16; ++r) {
                int row = (r & 3) + 8 * (r >> 2) + 4 * kgl;
                cp[(size_t)row * RES_DIM] = acc[mf][nf][r];
            }
        }
}

// ---------- fallback fp32 GEMM (only if ws too small) ----------
__global__ __launch_bounds__(256)
void gemm_f32(const float* __restrict__ A, const float* __restrict__ B, float* __restrict__ C) {
    __shared__ float sAf[64][33];
    __shared__ float sBf[64][33];
    const int tid = threadIdx.x;
    const int tx = tid & 15, ty = tid >> 4;
    const size_t t0 = (size_t)blockIdx.x * 64;
    const size_t r0 = (size_t)blockIdx.y * 64;
    const int lrow = tid >> 2;
    const int lcol = (tid & 3) * 8;
    float acc[4][4] = {};
    for (int k0 = 0; k0 < IN_DIM; k0 += 32) {
        float4 a0 = *(const float4*)&A[(t0 + lrow) * IN_DIM + k0 + lcol];
        float4 a1 = *(const float4*)&A[(t0 + lrow) * IN_DIM + k0 + lcol + 4];
        float4 b0 = *(const float4*)&B[(r0 + lrow) * IN_DIM + k0 + lcol];
        float4 b1 = *(const float4*)&B[(r0 + lrow) * IN_DIM + k0 + lcol + 4];
        __syncthreads();
        sAf[lrow][lcol + 0] = a0.x; sAf[lrow][lcol + 1] = a0.y;
        sAf[lrow][lcol + 2] = a0.z; sAf[lrow][lcol + 3] = a0.w;
        sAf[lrow][lcol + 4] = a1.x; sAf[lrow][lcol + 5] = a1.y;
        sAf[lrow][lcol + 6] = a1.z; sAf[lrow][lcol + 7] = a1.w;
        sBf[lrow][lcol + 0] = b0.x; sBf[lrow][lcol + 1] = b0.y;
        sBf[lrow][lcol + 2] = b0.z; sBf[lrow][lcol + 3] = b0.w;
        sBf[lrow][lcol + 4] = b1.x; sBf[lrow][lcol + 5] = b1.y;
        sBf[lrow][lcol + 6] = b1.z; sBf[lrow][lcol + 7] = b1.w;
        __syncthreads();
#pragma unroll
        for (int kk = 0; kk < 32; ++kk) {
            float av[4], bv[4];
#pragma unroll
            for (int i = 0; i < 4; ++i) av[i] = sAf[ty * 4 + i][kk];
#pragma unroll
            for (int j = 0; j < 4; ++j) bv[j] = sBf[tx * 4 + j][kk];
#pragma unroll
            for (int i = 0; i < 4; ++i)
#pragma unroll
                for (int j = 0; j < 4; ++j) acc[i][j] = fmaf(av[i], bv[j], acc[i][j]);
        }
    }
#pragma unroll
    for (int i = 0; i < 4; ++i)
#pragma unroll
        for (int j = 0; j < 4; ++j)
            C[(t0 + ty * 4 + i) * RES_DIM + r0 + tx * 4 + j] = acc[i][j];
}

// ---------- scan part A: warmup seeds (float2, unchanged from rounds 6-10) ----------
__global__ void warmup2_kernel(const float* __restrict__ U, const float* __restrict__ d,
                               float* __restrict__ sinit, int C, int W, int NC) {
    int g = blockIdx.x * blockDim.x + threadIdx.x;
    if (g >= NC * (RES_DIM / 2)) return;
    int c = g >> 11;              // / 2048
    int r2 = g & 2047;
    float2 s = make_float2(0.0f, 0.0f);
    if (c > 0) {
        float2 dr = ((const float2*)d)[r2];
        const float2* p = (const float2*)U + (size_t)(c * C - W) * 2048 + r2;
        constexpr int PF = 8;
        float2 buf[PF];
#pragma unroll
        for (int i = 0; i < PF; ++i) buf[i] = p[(size_t)i * 2048];
        for (int t = 0; t < W; t += PF) {
#pragma unroll
            for (int j = 0; j < PF; ++j) {
                float2 u = buf[j];
                int tn = t + j + PF;
                if (tn < W) buf[j] = p[(size_t)tn * 2048];
                s.x = tanh_fast(fmaf(dr.x, s.x, u.x));
                s.y = tanh_fast(fmaf(dr.y, s.y, u.y));
            }
        }
    }
    ((float2*)sinit)[g] = s;
}

// ---------- scan part B: in-place chunked scan (float2, unchanged from rounds 6-10) ----------
__global__ void scan2_kernel(float* __restrict__ U, const float* __restrict__ d,
                             const float* __restrict__ sinit, int C, int NC) {
    int g = blockIdx.x * blockDim.x + threadIdx.x;
    if (g >= NC * (RES_DIM / 2)) return;
    int c = g >> 11;
    int r2 = g & 2047;
    float2 dr = ((const float2*)d)[r2];
    float2 s = (c == 0) ? make_float2(0.0f, 0.0f) : ((const float2*)sinit)[g];
    float2* p = (float2*)U + (size_t)c * C * 2048 + r2;
    constexpr int PF = 8;
    float2 buf[PF];
#pragma unroll
    for (int i = 0; i < PF; ++i) buf[i] = p[(size_t)i * 2048];
    for (int t = 0; t < C; t += PF) {
#pragma unroll
        for (int j = 0; j < PF; ++j) {
            float2 u = buf[j];
            int tn = t + j + PF;
            if (tn < C) buf[j] = p[(size_t)tn * 2048];   // prefetch ahead of the chain
            s.x = tanh_fast(fmaf(dr.x, s.x, u.x));
            s.y = tanh_fast(fmaf(dr.y, s.y, u.y));
            p[(size_t)(t + j) * 2048] = s;
        }
    }
}

// ---------- launch ----------
extern "C" void kernel_launch(void* const* d_in, const int* in_sizes, int n_in,
                              void* d_out, int out_size, void* d_ws, size_t ws_size,
                              hipStream_t stream) {
    const float* x    = (const float*)d_in[0];   // [T, 1024, 1]
    const float* W_in = (const float*)d_in[1];   // [4096, 1024]
    const float* dvec = (const float*)d_in[2];   // [4096]
    float* out = (float*)d_out;                  // [T, 4096]

    constexpr int NC   = 64;
    constexpr int CHK  = T_DIM / NC;   // 128
    constexpr int WARM = 64;

    const size_t szX = (size_t)T_DIM * IN_DIM * sizeof(u16);   // 16 MiB each (hi, lo)
    const size_t szW = (size_t)RES_DIM * IN_DIM * sizeof(u16); // 8 MiB
    const size_t szS = (size_t)NC * RES_DIM * sizeof(float);   // 1 MiB

    if (ws_size >= 2 * szX + szW + szS) {
        u16* Xh = (u16*)d_ws;
        u16* Xl = Xh + (size_t)T_DIM * IN_DIM;
        u16* Wf = Xl + (size_t)T_DIM * IN_DIM;
        float* sinit = (float*)(Wf + (size_t)RES_DIM * IN_DIM);

        const int nX   = T_DIM * IN_DIM / 8;     // 1048576
        const int nTot = nX + RES_DIM * IN_DIM / 8;
        convert_all<<<3072, 256, 0, stream>>>(x, W_in, Xh, Xl, Wf, nX, nTot);
        gemm_f16_wide2<<<dim3(T_DIM / 128, RES_DIM / 256), 256, 0, stream>>>(Xh, Xl, Wf, out);
        warmup2_kernel<<<NC * (RES_DIM / 2) / 256, 256, 0, stream>>>(out, dvec, sinit, CHK, WARM, NC);
        scan2_kernel<<<NC * (RES_DIM / 2) / 256, 256, 0, stream>>>(out, dvec, sinit, CHK, NC);
    } else {
        gemm_f32<<<dim3(T_DIM / 64, RES_DIM / 64), 256, 0, stream>>>(x, W_in, out);
        if (ws_size >= szS) {
            float* sinit = (float*)d_ws;
            warmup2_kernel<<<NC * (RES_DIM / 2) / 256, 256, 0, stream>>>(out, dvec, sinit, CHK, WARM, NC);
            scan2_kernel<<<NC * (RES_DIM / 2) / 256, 256, 0, stream>>>(out, dvec, sinit, CHK, NC);
        } else {
            scan2_kernel<<<(RES_DIM / 2) / 256, 256, 0, stream>>>(out, dvec, nullptr, T_DIM, 1);
        }
    }
}